// Round 8
// baseline (702.254 us; speedup 1.0000x reference)
//
#include <hip/hip_runtime.h>

// Q4_0 quantized linear: out[16, 11008] = x[16, 4096] @ ((w_q-8)*w_scale).T + bias
// All fp32; w_q holds int32 nibble values in [0,16).
//
// R8: double-buffered w staging (T3-minimum 2-phase).
// Evidence chain: R0/R4/R7 -- three different structures -- all plateau at
// ~105 us with VALUBusy ~15% (= ~16 us of real work). Common cause: stage
// latency and compute NEVER overlap within a wave (R0/R4: stage -> barrier
// -> compute convoy; R7: uncoalesced 64-line lane streams). Fix per the
// catalog's T3 minimum: TWO ws buffers; issue stage(next sub) BEFORE
// compute(current sub); ONE barrier per sub. By barrier time the loads had
// a ~2300-cycle compute phase to land -> the vmcnt(0) drain is free.
//  - sub loop fully unrolled -> buffer ping-pong is compile-time static
//    (rule #20; also lets the scheduler interleave pack/writes into FMAs).
//  - R=2, CK=128: LDS = xs 10K + 2x18K = 46K -> 3 blocks/CU; grid 22x32
//    = 704 blocks = 2.75/CU. 32 k-splits -> 5.6M atomics (~22 MB).
//  - __launch_bounds__(256,2) (VGPR cap 128): the one proven-non-spilling
//    setting for this family (R6: 128 VGPR, no spill; N=3 fits only the
//    exact R0 body; N=4 spills; no hint balloons to 256).
//  - stage mapping = R0's proven coalesced form: 8 lanes read 128
//    contiguous bytes of one row (dwordx4), 8 rows per wave-instr.
// Floors: VALU ~13 us; w-stream 180 MB -> 18-29 us (partial L3 residency).

constexpr int T       = 16;
constexpr int IN      = 4096;
constexpr int OUT     = 11008;
constexpr int NSCALE  = IN / 32;        // 128 scales per row
constexpr int THREADS = 256;
constexpr int R       = 2;              // rows per thread
constexpr int ROWSB   = THREADS * R;    // 512 rows per block
constexpr int CK      = 128;            // k per block -> 32 k-splits
constexpr int WSUB    = 32;             // k per stage (== Q4_0 block size)
constexpr int NSUB    = CK / WSUB;      // 4
constexpr int WSTRIDE = 36;             // ws row stride bytes (32 + 4 pad -> 9 words, 2-way = free)
constexpr int XPAD    = 20;             // xs row stride floats (80 B, 16-B aligned)
constexpr int LD4     = (ROWSB * WSUB / 4) / THREADS;  // 16 int4 per thread per sub

__global__ __launch_bounds__(THREADS, 2) void qlinear_dbuf(
    const float* __restrict__ x,        // [T, IN]
    const int*   __restrict__ w_q,      // [OUT, IN]
    const float* __restrict__ w_scale,  // [OUT, NSCALE]
    const float* __restrict__ bias,     // [OUT]
    float* __restrict__ out)            // [T, OUT] (pre-zeroed)
{
    __shared__ __align__(16) float         xs[CK][XPAD];          // 10 KiB
    __shared__ __align__(16) unsigned char wsA[ROWSB * WSTRIDE];  // 18 KiB
    __shared__ __align__(16) unsigned char wsB[ROWSB * WSTRIDE];  // 18 KiB

    const int tid  = threadIdx.x;
    const int row0 = blockIdx.x * ROWSB;
    const int k0   = blockIdx.y * CK;

    // ---- stage x chunk transposed: xs[k][t] = x[t][k0+k] (coalesced) ----
    #pragma unroll
    for (int it = 0; it < CK * T / THREADS; ++it) {  // 8
        int idx = it * THREADS + tid;
        int t   = idx >> 7;          // idx / CK
        int k   = idx & (CK - 1);
        xs[k][t] = x[t * IN + k0 + k];
    }

    // ---- per-row scales for the 4 sub-blocks of this k-chunk ----
    float4 sc[R];
    #pragma unroll
    for (int r = 0; r < R; ++r) {
        int rg = min(row0 + tid + r * THREADS, OUT - 1);
        sc[r] = *(const float4*)(w_scale + rg * NSCALE + (k0 >> 5));
    }

    // ---- coalesced w stage: flat int4 id f -> row rr=f/8, chunk j=f%8;
    //      lanes 0..7 read 128 contiguous bytes of one row. ----
    auto stage_w = [&](unsigned char* buf, int s) {
        #pragma unroll 4
        for (int it = 0; it < LD4; ++it) {           // 16, 4 int4 in flight
            int f  = it * THREADS + tid;
            int rr = f >> 3;
            int j  = f & 7;
            int rg = min(row0 + rr, OUT - 1);
            const int4 v = *(const int4*)(w_q + (size_t)rg * IN + k0 + s * WSUB + j * 4);
            unsigned int u = (unsigned)v.x | ((unsigned)v.y << 8) |
                             ((unsigned)v.z << 16) | ((unsigned)v.w << 24);
            *(unsigned int*)(buf + rr * WSTRIDE + j * 4) = u;
        }
    };

    float acc[R][T];
    #pragma unroll
    for (int r = 0; r < R; ++r)
        #pragma unroll
        for (int t = 0; t < T; ++t) acc[r][t] = 0.0f;

    // ---- prologue: fill buffer A with sub 0 ----
    stage_w(wsA, 0);
    __syncthreads();    // wsA + xs ready

    #pragma unroll
    for (int sub = 0; sub < NSUB; ++sub) {           // 4, fully unrolled
        unsigned char* cur = (sub & 1) ? wsB : wsA;  // compile-time per copy
        unsigned char* nxt = (sub & 1) ? wsA : wsB;

        // ---- issue next sub's stage FIRST: writes nxt, reads cur --
        //      no intra-sub barrier; latency hides under compute below ----
        if (sub + 1 < NSUB) stage_w(nxt, sub + 1);

        float s[R], s8[R];
        #pragma unroll
        for (int r = 0; r < R; ++r) {
            float sv = (sub == 0) ? sc[r].x : (sub == 1) ? sc[r].y
                     : (sub == 2) ? sc[r].z : sc[r].w;   // sub is constant
            s[r]  = sv;
            s8[r] = -8.0f * sv;   // exact
        }

        for (int k4 = 0; k4 < WSUB / 4; ++k4) {      // 8 (rolled)
            unsigned int q[R];
            #pragma unroll
            for (int r = 0; r < R; ++r)
                q[r] = *(const unsigned int*)(cur + (tid + r * THREADS) * WSTRIDE + k4 * 4);

            #pragma unroll
            for (int kk = 0; kk < 4; ++kk) {
                const float4* xp = (const float4*)&xs[sub * WSUB + k4 * 4 + kk][0];
                float4 x0 = xp[0], x1 = xp[1], x2 = xp[2], x3 = xp[3];
                #pragma unroll
                for (int r = 0; r < R; ++r) {
                    // (q - 8) * s with a single rounding; byte extract is
                    // kk-constant -> v_cvt_f32_ubyte{kk}
                    float wv = fmaf((float)((q[r] >> (8 * kk)) & 0xffu), s[r], s8[r]);
                    acc[r][0]  = fmaf(wv, x0.x, acc[r][0]);
                    acc[r][1]  = fmaf(wv, x0.y, acc[r][1]);
                    acc[r][2]  = fmaf(wv, x0.z, acc[r][2]);
                    acc[r][3]  = fmaf(wv, x0.w, acc[r][3]);
                    acc[r][4]  = fmaf(wv, x1.x, acc[r][4]);
                    acc[r][5]  = fmaf(wv, x1.y, acc[r][5]);
                    acc[r][6]  = fmaf(wv, x1.z, acc[r][6]);
                    acc[r][7]  = fmaf(wv, x1.w, acc[r][7]);
                    acc[r][8]  = fmaf(wv, x2.x, acc[r][8]);
                    acc[r][9]  = fmaf(wv, x2.y, acc[r][9]);
                    acc[r][10] = fmaf(wv, x2.z, acc[r][10]);
                    acc[r][11] = fmaf(wv, x2.w, acc[r][11]);
                    acc[r][12] = fmaf(wv, x3.x, acc[r][12]);
                    acc[r][13] = fmaf(wv, x3.y, acc[r][13]);
                    acc[r][14] = fmaf(wv, x3.z, acc[r][14]);
                    acc[r][15] = fmaf(wv, x3.w, acc[r][15]);
                }
            }
        }

        // one barrier per sub: (a) nxt's writes visible before sub+1 reads
        // them, (b) all waves done reading cur before sub+2 overwrites it.
        // Loads issued above have had the whole compute phase to land, so
        // the compiler's vmcnt(0) drain here is ~free.
        __syncthreads();
    }

    // ---- epilogue: bias (split 0 only) + atomic combine across splits ----
    const bool add_b = (blockIdx.y == 0);
    #pragma unroll
    for (int r = 0; r < R; ++r) {
        int rg = row0 + tid + r * THREADS;
        if (rg < OUT) {
            float b = add_b ? bias[rg] : 0.0f;
            #pragma unroll
            for (int t = 0; t < T; ++t)
                atomicAdd(out + t * OUT + rg, acc[r][t] + b);
        }
    }
}

extern "C" void kernel_launch(void* const* d_in, const int* in_sizes, int n_in,
                              void* d_out, int out_size, void* d_ws, size_t ws_size,
                              hipStream_t stream) {
    const float* x       = (const float*)d_in[0];
    const int*   w_q     = (const int*)d_in[1];
    const float* w_scale = (const float*)d_in[2];
    const float* bias    = (const float*)d_in[3];
    float*       out     = (float*)d_out;

    // Zero the (0xAA-poisoned) output; captured as a graph memset node.
    hipMemsetAsync(d_out, 0, (size_t)out_size * sizeof(float), stream);

    dim3 grid((OUT + ROWSB - 1) / ROWSB, IN / CK);   // 22 x 32 = 704 blocks
    qlinear_dbuf<<<grid, THREADS, 0, stream>>>(x, w_q, w_scale, bias, out);
}